// Round 9
// baseline (269.116 us; speedup 1.0000x reference)
//
#include <hip/hip_runtime.h>
#include <stdint.h>

#define S_LEN  2048
#define BATCH  2
#define DMODEL 1024
#define NHEAD  16
#define DKH    64

typedef __attribute__((ext_vector_type(8))) __bf16 bf16x8;
typedef __attribute__((ext_vector_type(4))) float  f32x4;
typedef unsigned short u16;
typedef unsigned int   u32;

#if __has_builtin(__builtin_amdgcn_exp2f)
#define EXP2(x) __builtin_amdgcn_exp2f(x)
#else
#define EXP2(x) __expf(0.69314718055994531f * (x))
#endif

// v_permlane32_swap: vdst lanes 32-63 <-> vsrc lanes 0-31
#define SWAP32(a, b) asm("v_permlane32_swap_b32 %0, %1" : "+v"(a), "+v"(b))
// v_permlane16_swap: vdst lanes 16-31,48-63 <-> vsrc lanes 0-15,32-47
#define SWAP16(a, b) asm("v_permlane16_swap_b32 %0, %1" : "+v"(a), "+v"(b))

__device__ __forceinline__ u16 f2bf(float f) {
  union { float f; u32 u; } v; v.f = f;
  u32 r = v.u + 0x7fffu + ((v.u >> 16) & 1u);
  return (u16)(r >> 16);
}

// ---------------- fused fp32 -> bf16 conversion (1 launch, 7 tensors) ----------------
__global__ void cvt_all(const float4* __restrict__ q, const float4* __restrict__ k,
                        const float4* __restrict__ v,
                        const float4* __restrict__ wq, const float4* __restrict__ wk,
                        const float4* __restrict__ wv, const float4* __restrict__ wo,
                        ushort4* __restrict__ dst) {
  const int NX4 = (S_LEN * BATCH * DMODEL) / 4;  // 2^20
  const int NW4 = (DMODEL * DMODEL) / 4;         // 2^18
  int i = blockIdx.x * blockDim.x + threadIdx.x;
  const float4* src;
  int off;
  if (i < 3 * NX4) {
    src = (i < NX4) ? q : (i < 2 * NX4) ? k : v;
    off = i & (NX4 - 1);
  } else {
    int j = i - 3 * NX4;
    int t = j >> 18;
    src = (t == 0) ? wq : (t == 1) ? wk : (t == 2) ? wv : wo;
    off = j & (NW4 - 1);
  }
  float4 val = src[off];
  ushort4 o;
  o.x = f2bf(val.x); o.y = f2bf(val.y); o.z = f2bf(val.z); o.w = f2bf(val.w);
  dst[i] = o;
}

// ---------------- Fused Q/K/V projection GEMM (XCD-swizzled, BK=64) ----------------
// BK=64 halves barrier count vs BK=32 (the m97 ~20% vmcnt-drain stall amortizes 2x).
// [128][64] tiles are 128B-row-aligned -> XOR-swizzled gload_lds source + same-XOR
// read (attn-v7 proven pattern) keeps ds_read_b128 at the b128 floor.
__global__ __launch_bounds__(256, 2)
void gemm_qkv(const u16* __restrict__ Abase, const u16* __restrict__ Wbase,
              const float* __restrict__ b0, const float* __restrict__ b1,
              const float* __restrict__ b2, u16* __restrict__ Obase) {
  __shared__ __align__(16) u16 As[128 * 64];
  __shared__ __align__(16) u16 Bs[128 * 64];

  const int L = blockIdx.x + (blockIdx.y << 3) + (blockIdx.z << 8);  // 0..767
  const int xcd = L & 7, sl = L >> 3;      // sl 0..95
  const int z  = sl >> 5;
  const int y  = xcd * 4 + ((sl >> 3) & 3);
  const int nx = sl & 7;

  const u16* A = Abase + (size_t)z * (S_LEN * BATCH * DMODEL);
  const u16* W = Wbase + (size_t)z * (DMODEL * DMODEL);
  const float* bias = (z == 0) ? b0 : (z == 1) ? b1 : b2;
  u16* O = Obase + (size_t)z * (S_LEN * BATCH * DMODEL);
  const float scl = (z == 0) ? 1.4426950408889634f : 1.0f;

  const int tid  = threadIdx.x;
  const int wave = tid >> 6, lane = tid & 63;
  const int quad = lane >> 4, lcol = lane & 15;
  const int m0 = y * 128, n0 = nx * 128;
  const int wm = (wave >> 1) * 64, wn = (wave & 1) * 64;
  const int x7 = lcol & 7;

  // staging: LDS[row][chunk] = G[row][chunk ^ (row&7)] (16B chunks, 8/row)
  const int srow = tid >> 3;                               // 0..31 (+32 per r)
  const int scol = ((tid & 7) ^ ((tid >> 3) & 7)) * 8;     // pre-swizzled source col (u16)

  f32x4 acc[4][4] = {};

  for (int k0 = 0; k0 < DMODEL; k0 += 64) {
#pragma unroll
    for (int r = 0; r < 4; ++r) {
      int row = r * 32 + srow;
      const u16* gA = A + (size_t)(m0 + row) * DMODEL + k0 + scol;
      const u16* gW = W + (size_t)(n0 + row) * DMODEL + k0 + scol;
      u16* lA = As + (size_t)(r * 256 + (tid & 192)) * 8;
      u16* lB = Bs + (size_t)(r * 256 + (tid & 192)) * 8;
      __builtin_amdgcn_global_load_lds((const __attribute__((address_space(1))) void*)gA,
                                       (__attribute__((address_space(3))) void*)lA, 16, 0, 0);
      __builtin_amdgcn_global_load_lds((const __attribute__((address_space(1))) void*)gW,
                                       (__attribute__((address_space(3))) void*)lB, 16, 0, 0);
    }
    __syncthreads();

#pragma unroll
    for (int c = 0; c < 2; ++c) {
      const int chk = (((c << 2) | quad) ^ x7) << 3;   // swizzled read chunk (u16 off)
      bf16x8 af[4], bfr[4];
#pragma unroll
      for (int i = 0; i < 4; ++i) af[i]  = *(const bf16x8*)(As + (wm + i * 16 + lcol) * 64 + chk);
#pragma unroll
      for (int j = 0; j < 4; ++j) bfr[j] = *(const bf16x8*)(Bs + (wn + j * 16 + lcol) * 64 + chk);
#pragma unroll
      for (int i = 0; i < 4; ++i)
#pragma unroll
        for (int j = 0; j < 4; ++j)
          acc[i][j] = __builtin_amdgcn_mfma_f32_16x16x32_bf16(af[i], bfr[j], acc[i][j], 0, 0, 0);
    }
    __syncthreads();
  }

#pragma unroll
  for (int i = 0; i < 4; ++i) {
#pragma unroll
    for (int j = 0; j < 4; ++j) {
      int n = n0 + wn + j * 16 + lcol;
      int h = n >> 6, dk = n & 63;
      float bv = bias[n];
#pragma unroll
      for (int r = 0; r < 4; ++r) {
        int m = m0 + wm + i * 16 + quad * 4 + r;
        int s = m >> 1, b = m & 1;
        O[((size_t)(b * NHEAD + h) * S_LEN + s) * DKH + dk] = f2bf((acc[i][j][r] + bv) * scl);
      }
    }
  }
}

// ---------------- Output projection GEMM: 128(M) x 64(N), BK=64, fp32 out ----------------
__global__ __launch_bounds__(256, 2)
void gemm_o(const u16* __restrict__ A, const u16* __restrict__ W,
            const float* __restrict__ bias, float* __restrict__ O) {
  __shared__ __align__(16) u16 As[128 * 64];
  __shared__ __align__(16) u16 Bs[64 * 64];

  const int L = blockIdx.x + (blockIdx.y << 4);  // 0..511
  const int xcd = L & 7, sl = L >> 3;            // sl 0..63
  const int y = xcd * 4 + (sl >> 4);
  const int x = sl & 15;

  const int tid  = threadIdx.x;
  const int wave = tid >> 6, lane = tid & 63;
  const int quad = lane >> 4, lcol = lane & 15;
  const int m0 = y * 128, n0 = x * 64;
  const int wm = (wave >> 1) * 64, wn = (wave & 1) * 32;
  const int x7 = lcol & 7;

  const int srow = tid >> 3;
  const int scol = ((tid & 7) ^ ((tid >> 3) & 7)) * 8;

  f32x4 acc[4][2] = {};

  for (int k0 = 0; k0 < DMODEL; k0 += 64) {
#pragma unroll
    for (int r = 0; r < 4; ++r) {
      int row = r * 32 + srow;
      const u16* gA = A + (size_t)(m0 + row) * DMODEL + k0 + scol;
      u16* lA = As + (size_t)(r * 256 + (tid & 192)) * 8;
      __builtin_amdgcn_global_load_lds((const __attribute__((address_space(1))) void*)gA,
                                       (__attribute__((address_space(3))) void*)lA, 16, 0, 0);
    }
#pragma unroll
    for (int r = 0; r < 2; ++r) {
      int row = r * 32 + srow;
      const u16* gW = W + (size_t)(n0 + row) * DMODEL + k0 + scol;
      u16* lB = Bs + (size_t)(r * 256 + (tid & 192)) * 8;
      __builtin_amdgcn_global_load_lds((const __attribute__((address_space(1))) void*)gW,
                                       (__attribute__((address_space(3))) void*)lB, 16, 0, 0);
    }
    __syncthreads();

#pragma unroll
    for (int c = 0; c < 2; ++c) {
      const int chk = (((c << 2) | quad) ^ x7) << 3;
      bf16x8 af[4], bfr[2];
#pragma unroll
      for (int i = 0; i < 4; ++i) af[i]  = *(const bf16x8*)(As + (wm + i * 16 + lcol) * 64 + chk);
#pragma unroll
      for (int j = 0; j < 2; ++j) bfr[j] = *(const bf16x8*)(Bs + (wn + j * 16 + lcol) * 64 + chk);
#pragma unroll
      for (int i = 0; i < 4; ++i)
#pragma unroll
        for (int j = 0; j < 2; ++j)
          acc[i][j] = __builtin_amdgcn_mfma_f32_16x16x32_bf16(af[i], bfr[j], acc[i][j], 0, 0, 0);
    }
    __syncthreads();
  }

#pragma unroll
  for (int i = 0; i < 4; ++i) {
#pragma unroll
    for (int j = 0; j < 2; ++j) {
      int n = n0 + wn + j * 16 + lcol;
      float bv = bias[n];
#pragma unroll
      for (int r = 0; r < 4; ++r) {
        int m = m0 + wm + i * 16 + quad * 4 + r;
        O[(size_t)m * DMODEL + n] = acc[i][j][r] + bv;
      }
    }
  }
}

// ---------------- Flash attention v7.1: v7 + unroll-2 main loop ----------------
// Q,K,V: [B*H, S, DK] bf16 (Q pre-scaled by log2 e). Output: [S*B, D] bf16.
// 8 waves/512 thr: qg = wave&3 (32 q-rows), kh = wave>>2 (kv half). Q-tile 128,
// grid 512 = 2 blocks/CU -> 16 waves/CU. Double-buffered K/V, ONE barrier/iter.
// K staged by global_load_lds with XOR-pre-swizzled source; ds_read same-XOR.
// unroll 2 makes `cur` compile-time (kills per-iter buffer-select VALU).
__global__ __launch_bounds__(512, 4)
void attn_kernel(const u16* __restrict__ Q, const u16* __restrict__ K,
                 const u16* __restrict__ V, u16* __restrict__ O) {
  __shared__ __align__(16) u16 Ks[2][128 * 64];
  __shared__ __align__(16) u16 Vts[2][2 * 4608];
  __shared__ float ls2[4][2][16];

  const int tid  = threadIdx.x;
  const int wave = tid >> 6, lane = tid & 63;
  const int quad = lane >> 4, lcol = lane & 15;
  const int qg = wave & 3;    // q group: 32 rows
  const int kh = wave >> 2;   // kv half

  // bijective XCD swizzle: XCD c gets heads {4c..4c+3} x 16 q-tiles
  const int L = blockIdx.x + (blockIdx.y << 4);  // 0..511
  const int xcd = L & 7, slot = L >> 3;          // slot 0..63
  const int bh = xcd * 4 + (slot >> 4);
  const int q0 = (slot & 15) * 128;

  const size_t headOff = (size_t)bh * S_LEN * DKH;
  const u16* Qg = Q + headOff;
  const u16* Kg = K + headOff;
  const u16* Vg = V + headOff;

  // Q fragments in registers
  bf16x8 qf[2][2];
#pragma unroll
  for (int s = 0; s < 2; ++s)
#pragma unroll
    for (int kc = 0; kc < 2; ++kc)
      qf[s][kc] = *(const bf16x8*)(Qg + (size_t)(q0 + qg * 32 + s * 16 + lcol) * DKH +
                                   kc * 32 + quad * 8);

  // K staging via gload_lds: wave-linear dest, XOR-swizzled source column.
  const int krow = tid >> 3;                                   // 0..63 (local row)
  const int kcs  = (((tid & 7) ^ ((tid >> 3) & 7))) * 8;       // src col (u16)
  const int kdst = (tid & 448) * 8;                            // u16: wave*512 (wave-uniform)
  // V staging roles
  const int vhalf = lane >> 5, vkp = lane & 31, vo = wave;

  // ---- prologue: stage tile 0 -> buf 0
  {
    const u16* vp = Vg + (size_t)(vhalf * (S_LEN / 2) + 2 * vkp) * DKH + 8 * vo;
    uint4 vr0 = *(const uint4*)vp;
    uint4 vr1 = *(const uint4*)(vp + DKH);
    __builtin_amdgcn_global_load_lds(
        (const __attribute__((address_space(1))) void*)(Kg + (size_t)krow * DKH + kcs),
        (__attribute__((address_space(3))) void*)(Ks[0] + kdst), 16, 0, 0);
    __builtin_amdgcn_global_load_lds(
        (const __attribute__((address_space(1))) void*)(Kg + (size_t)(S_LEN / 2 + krow) * DKH + kcs),
        (__attribute__((address_space(3))) void*)(Ks[0] + 4096 + kdst), 16, 0, 0);
    u16* vd = Vts[0] + vhalf * 4608;
#pragma unroll
    for (int jj = 0; jj < 4; ++jj) {
      u32 aw = ((const u32*)&vr0)[jj], bw = ((const u32*)&vr1)[jj];
      *(u32*)(vd + (size_t)(8 * vo + 2 * jj) * 72 + 2 * vkp)     = __builtin_amdgcn_perm(bw, aw, 0x05040100u);
      *(u32*)(vd + (size_t)(8 * vo + 2 * jj + 1) * 72 + 2 * vkp) = __builtin_amdgcn_perm(bw, aw, 0x07060302u);
    }
  }

  f32x4 o_acc[2][4] = {};
  float lsum[2] = {0.f, 0.f};

#pragma unroll 2
  for (int it = 0; it < 16; ++it) {
    const int cur = it & 1;
    __syncthreads();  // buf[cur] complete (compiler drains vmcnt+lgkm before s_barrier)

    // prefetch tile it+1 into buf[cur^1]: V->regs, K->LDS direct
    uint4 vr0, vr1;
    const bool has = (it < 15);
    if (has) {
      const int nb = (it + 1) * 64;
      const u16* vp = Vg + (size_t)(vhalf * (S_LEN / 2) + nb + 2 * vkp) * DKH + 8 * vo;
      vr0 = *(const uint4*)vp;
      vr1 = *(const uint4*)(vp + DKH);
      __builtin_amdgcn_global_load_lds(
          (const __attribute__((address_space(1))) void*)(Kg + (size_t)(nb + krow) * DKH + kcs),
          (__attribute__((address_space(3))) void*)(Ks[cur ^ 1] + kdst), 16, 0, 0);
      __builtin_amdgcn_global_load_lds(
          (const __attribute__((address_space(1))) void*)(Kg + (size_t)(S_LEN / 2 + nb + krow) * DKH + kcs),
          (__attribute__((address_space(3))) void*)(Ks[cur ^ 1] + 4096 + kdst), 16, 0, 0);
    }

    const u16* kb = Ks[cur] + kh * 4096;   // this half's 64 rows (swizzled)
    const u16* vb = Vts[cur] + kh * 4608;

    // two 32-key groups; per group: QK -> softmax/pack -> PV
#pragma unroll
    for (int g = 0; g < 2; ++g) {
      bf16x8 ak[2][2];
#pragma unroll
      for (int jb = 0; jb < 2; ++jb)
#pragma unroll
        for (int kc = 0; kc < 2; ++kc)
          ak[jb][kc] = *(const bf16x8*)(kb + (g * 32 + jb * 16 + lcol) * 64 +
                                        ((((kc << 2) | quad) ^ (lcol & 7)) << 3));
      f32x4 sc[2][2] = {};
      __builtin_amdgcn_s_setprio(1);
#pragma unroll
      for (int kc = 0; kc < 2; ++kc)
#pragma unroll
        for (int jb = 0; jb < 2; ++jb)
#pragma unroll
          for (int s = 0; s < 2; ++s)
            sc[jb][s] = __builtin_amdgcn_mfma_f32_16x16x32_bf16(ak[jb][kc], qf[s][kc], sc[jb][s], 0, 0, 0);
      __builtin_amdgcn_s_setprio(0);

      // p = 2^s; pack + permlane redistribute into PV A-frags (in-register P)
      bf16x8 pa[2];
#pragma unroll
      for (int s = 0; s < 2; ++s) {
        u32 ww[2][2];
#pragma unroll
        for (int jb = 0; jb < 2; ++jb) {
          float p0 = EXP2(sc[jb][s][0]);
          float p1 = EXP2(sc[jb][s][1]);
          float p2 = EXP2(sc[jb][s][2]);
          float p3 = EXP2(sc[jb][s][3]);
          lsum[s] += (p0 + p1) + (p2 + p3);
          asm("v_cvt_pk_bf16_f32 %0, %1, %2" : "=v"(ww[jb][0]) : "v"(p0), "v"(p1));
          asm("v_cvt_pk_bf16_f32 %0, %1, %2" : "=v"(ww[jb][1]) : "v"(p2), "v"(p3));
        }
        u32 a0 = ww[0][0], b0 = ww[1][0];
        SWAP32(a0, b0); SWAP16(a0, b0);
        u32 a1 = ww[0][1], b1 = ww[1][1];
        SWAP32(a1, b1); SWAP16(a1, b1);
        union { u32 u[4]; bf16x8 v; } f;
        f.u[0] = a0; f.u[1] = a1; f.u[2] = b0; f.u[3] = b1;
        pa[s] = f.v;
      }

      bf16x8 bv[4];
#pragma unroll
      for (int jd = 0; jd < 4; ++jd)
        bv[jd] = *(const bf16x8*)(vb + (jd * 16 + lcol) * 72 + g * 32 + quad * 8);
      __builtin_amdgcn_s_setprio(1);
#pragma unroll
      for (int s = 0; s < 2; ++s)
#pragma unroll
        for (int jd = 0; jd < 4; ++jd)
          o_acc[s][jd] = __builtin_amdgcn_mfma_f32_16x16x32_bf16(pa[s], bv[jd], o_acc[s][jd], 0, 0, 0);
      __builtin_amdgcn_s_setprio(0);
    }

    // late V publish into buf[cur^1] (loads have had the whole compute to land)
    if (has) {
      u16* vd = Vts[cur ^ 1] + vhalf * 4608;
#pragma unroll
      for (int jj = 0; jj < 4; ++jj) {
        u32 aw = ((const u32*)&vr0)[jj], bw = ((const u32*)&vr1)[jj];
        *(u32*)(vd + (size_t)(8 * vo + 2 * jj) * 72 + 2 * vkp)     = __builtin_amdgcn_perm(bw, aw, 0x05040100u);
        *(u32*)(vd + (size_t)(8 * vo + 2 * jj + 1) * 72 + 2 * vkp) = __builtin_amdgcn_perm(bw, aw, 0x07060302u);
      }
    }
  }

  __syncthreads();  // ALL compute done before LDS is reused as combine scratch

  // reduce lsum over quads
#pragma unroll
  for (int s = 0; s < 2; ++s) {
    lsum[s] += __shfl_xor(lsum[s], 16);
    lsum[s] += __shfl_xor(lsum[s], 32);
  }

  // ---- cross-half combine (scratch on dead Vts: 9216 floats, stride 36 = bank-minimal)
  float* scr = (float*)Vts;
  const int cbase = (qg * 64 + lane) * 36;
  if (kh == 1) {
#pragma unroll
    for (int s = 0; s < 2; ++s)
#pragma unroll
      for (int jd = 0; jd < 4; ++jd)
        *(f32x4*)(scr + cbase + (s * 4 + jd) * 4) = o_acc[s][jd];
    if (lane < 16) {
#pragma unroll
      for (int s = 0; s < 2; ++s) ls2[qg][s][lane] = lsum[s];
    }
  }
  __syncthreads();
  if (kh == 0) {
#pragma unroll
    for (int s = 0; s < 2; ++s)
#pragma unroll
      for (int jd = 0; jd < 4; ++jd)
        o_acc[s][jd] += *(const f32x4*)(scr + cbase + (s * 4 + jd) * 4);

    float tot[2];
#pragma unroll
    for (int s = 0; s < 2; ++s) tot[s] = lsum[s] + ls2[qg][s][lcol];

    // epilogue: normalize, write [S*B, D] bf16
    const int b = bh >> 4, hh = bh & 15;
#pragma unroll
    for (int s = 0; s < 2; ++s) {
#pragma unroll
      for (int r = 0; r < 4; ++r) {
        float inv = 1.f / __shfl(tot[s], quad * 4 + r);  // lane quad*4+r has lcol==quad*4+r
        int sq = q0 + qg * 32 + s * 16 + quad * 4 + r;
#pragma unroll
        for (int jd = 0; jd < 4; ++jd) {
          int dk = jd * 16 + lcol;
          O[((size_t)(sq * BATCH + b)) * DMODEL + hh * DKH + dk] = f2bf(o_acc[s][jd][r] * inv);
        }
      }
    }
  }
}

// ---------------- launch ----------------
extern "C" void kernel_launch(void* const* d_in, const int* in_sizes, int n_in,
                              void* d_out, int out_size, void* d_ws, size_t ws_size,
                              hipStream_t stream) {
  const float* q  = (const float*)d_in[0];
  const float* k  = (const float*)d_in[1];
  const float* v  = (const float*)d_in[2];
  const float* Wq = (const float*)d_in[3];
  const float* bq = (const float*)d_in[4];
  const float* Wk = (const float*)d_in[5];
  const float* bk = (const float*)d_in[6];
  const float* Wv = (const float*)d_in[7];
  const float* bv = (const float*)d_in[8];
  const float* Wo = (const float*)d_in[9];
  const float* bo = (const float*)d_in[10];

  const int NX = S_LEN * BATCH * DMODEL;  // 4194304
  const int NW = DMODEL * DMODEL;         // 1048576

  u16* ws  = (u16*)d_ws;
  u16* Xq  = ws;                    // 3 contiguous activation tensors
  u16* Wqb = Xq  + 3 * (size_t)NX;  // 4 contiguous weight tensors
  u16* Qb  = Wqb + 4 * (size_t)NW;  // 3 contiguous [B,H,S,DK] outputs
  u16* Xo  = Qb  + 3 * (size_t)NX;  // attention out [S*B, D]

  u16* Wob = Wqb + 3 * (size_t)NW;
  u16* Kb  = Qb + NX, *Vb = Qb + 2 * (size_t)NX;

  const int n4 = (3 * NX + 4 * NW) / 4;  // 4194304
  cvt_all<<<n4 / 256, 256, 0, stream>>>((const float4*)q, (const float4*)k, (const float4*)v,
                                        (const float4*)Wq, (const float4*)Wk, (const float4*)Wv,
                                        (const float4*)Wo, (ushort4*)ws);

  dim3 gqkv(DMODEL / 128, (S_LEN * BATCH) / 128, 3);  // 768 blocks
  gemm_qkv<<<gqkv, 256, 0, stream>>>(Xq, Wqb, bq, bk, bv, Qb);

  dim3 ga(S_LEN / 128, BATCH * NHEAD);  // (16, 32) = 512 blocks, 512 threads
  attn_kernel<<<ga, 512, 0, stream>>>(Qb, Kb, Vb, Xo);

  dim3 go(DMODEL / 64, (S_LEN * BATCH) / 128);  // 512 blocks
  gemm_o<<<go, 256, 0, stream>>>(Xo, Wob, bo, (float*)d_out);
}

// Round 10
// 203.980 us; speedup vs baseline: 1.3193x; 1.3193x over previous
//
#include <hip/hip_runtime.h>
#include <stdint.h>

#define S_LEN  2048
#define BATCH  2
#define DMODEL 1024
#define NHEAD  16
#define DKH    64

typedef __attribute__((ext_vector_type(8))) __bf16 bf16x8;
typedef __attribute__((ext_vector_type(4))) float  f32x4;
typedef unsigned short u16;
typedef unsigned int   u32;

#if __has_builtin(__builtin_amdgcn_exp2f)
#define EXP2(x) __builtin_amdgcn_exp2f(x)
#else
#define EXP2(x) __expf(0.69314718055994531f * (x))
#endif

// v_permlane32_swap: vdst lanes 32-63 <-> vsrc lanes 0-31
#define SWAP32(a, b) asm("v_permlane32_swap_b32 %0, %1" : "+v"(a), "+v"(b))
// v_permlane16_swap: vdst lanes 16-31,48-63 <-> vsrc lanes 0-15,32-47
#define SWAP16(a, b) asm("v_permlane16_swap_b32 %0, %1" : "+v"(a), "+v"(b))

__device__ __forceinline__ u16 f2bf(float f) {
  union { float f; u32 u; } v; v.f = f;
  u32 r = v.u + 0x7fffu + ((v.u >> 16) & 1u);
  return (u16)(r >> 16);
}

// ---------------- fused fp32 -> bf16 conversion (1 launch, 7 tensors) ----------------
__global__ void cvt_all(const float4* __restrict__ q, const float4* __restrict__ k,
                        const float4* __restrict__ v,
                        const float4* __restrict__ wq, const float4* __restrict__ wk,
                        const float4* __restrict__ wv, const float4* __restrict__ wo,
                        ushort4* __restrict__ dst) {
  const int NX4 = (S_LEN * BATCH * DMODEL) / 4;  // 2^20
  const int NW4 = (DMODEL * DMODEL) / 4;         // 2^18
  int i = blockIdx.x * blockDim.x + threadIdx.x;
  const float4* src;
  int off;
  if (i < 3 * NX4) {
    src = (i < NX4) ? q : (i < 2 * NX4) ? k : v;
    off = i & (NX4 - 1);
  } else {
    int j = i - 3 * NX4;
    int t = j >> 18;
    src = (t == 0) ? wq : (t == 1) ? wk : (t == 2) ? wv : wo;
    off = j & (NW4 - 1);
  }
  float4 val = src[off];
  ushort4 o;
  o.x = f2bf(val.x); o.y = f2bf(val.y); o.z = f2bf(val.z); o.w = f2bf(val.w);
  dst[i] = o;
}

// ---------------- Fused Q/K/V projection GEMM (XCD-swizzled, BK=64) ----------------
// BK=64 halves barrier count vs BK=32. [128][64] tiles are 128B-row-aligned ->
// XOR-swizzled gload_lds source + same-XOR read keeps ds_read_b128 at the floor.
__global__ __launch_bounds__(256, 2)
void gemm_qkv(const u16* __restrict__ Abase, const u16* __restrict__ Wbase,
              const float* __restrict__ b0, const float* __restrict__ b1,
              const float* __restrict__ b2, u16* __restrict__ Obase) {
  __shared__ __align__(16) u16 As[128 * 64];
  __shared__ __align__(16) u16 Bs[128 * 64];

  const int L = blockIdx.x + (blockIdx.y << 3) + (blockIdx.z << 8);  // 0..767
  const int xcd = L & 7, sl = L >> 3;      // sl 0..95
  const int z  = sl >> 5;
  const int y  = xcd * 4 + ((sl >> 3) & 3);
  const int nx = sl & 7;

  const u16* A = Abase + (size_t)z * (S_LEN * BATCH * DMODEL);
  const u16* W = Wbase + (size_t)z * (DMODEL * DMODEL);
  const float* bias = (z == 0) ? b0 : (z == 1) ? b1 : b2;
  u16* O = Obase + (size_t)z * (S_LEN * BATCH * DMODEL);
  const float scl = (z == 0) ? 1.4426950408889634f : 1.0f;

  const int tid  = threadIdx.x;
  const int wave = tid >> 6, lane = tid & 63;
  const int quad = lane >> 4, lcol = lane & 15;
  const int m0 = y * 128, n0 = nx * 128;
  const int wm = (wave >> 1) * 64, wn = (wave & 1) * 64;
  const int x7 = lcol & 7;

  // staging: LDS[row][chunk] = G[row][chunk ^ (row&7)] (16B chunks, 8/row)
  const int srow = tid >> 3;                               // 0..31 (+32 per r)
  const int scol = ((tid & 7) ^ ((tid >> 3) & 7)) * 8;     // pre-swizzled source col (u16)

  f32x4 acc[4][4] = {};

  for (int k0 = 0; k0 < DMODEL; k0 += 64) {
#pragma unroll
    for (int r = 0; r < 4; ++r) {
      int row = r * 32 + srow;
      const u16* gA = A + (size_t)(m0 + row) * DMODEL + k0 + scol;
      const u16* gW = W + (size_t)(n0 + row) * DMODEL + k0 + scol;
      u16* lA = As + (size_t)(r * 256 + (tid & 192)) * 8;
      u16* lB = Bs + (size_t)(r * 256 + (tid & 192)) * 8;
      __builtin_amdgcn_global_load_lds((const __attribute__((address_space(1))) void*)gA,
                                       (__attribute__((address_space(3))) void*)lA, 16, 0, 0);
      __builtin_amdgcn_global_load_lds((const __attribute__((address_space(1))) void*)gW,
                                       (__attribute__((address_space(3))) void*)lB, 16, 0, 0);
    }
    __syncthreads();

#pragma unroll
    for (int c = 0; c < 2; ++c) {
      const int chk = (((c << 2) | quad) ^ x7) << 3;   // swizzled read chunk (u16 off)
      bf16x8 af[4], bfr[4];
#pragma unroll
      for (int i = 0; i < 4; ++i) af[i]  = *(const bf16x8*)(As + (wm + i * 16 + lcol) * 64 + chk);
#pragma unroll
      for (int j = 0; j < 4; ++j) bfr[j] = *(const bf16x8*)(Bs + (wn + j * 16 + lcol) * 64 + chk);
#pragma unroll
      for (int i = 0; i < 4; ++i)
#pragma unroll
        for (int j = 0; j < 4; ++j)
          acc[i][j] = __builtin_amdgcn_mfma_f32_16x16x32_bf16(af[i], bfr[j], acc[i][j], 0, 0, 0);
    }
    __syncthreads();
  }

#pragma unroll
  for (int i = 0; i < 4; ++i) {
#pragma unroll
    for (int j = 0; j < 4; ++j) {
      int n = n0 + wn + j * 16 + lcol;
      int h = n >> 6, dk = n & 63;
      float bv = bias[n];
#pragma unroll
      for (int r = 0; r < 4; ++r) {
        int m = m0 + wm + i * 16 + quad * 4 + r;
        int s = m >> 1, b = m & 1;
        O[((size_t)(b * NHEAD + h) * S_LEN + s) * DKH + dk] = f2bf((acc[i][j][r] + bv) * scl);
      }
    }
  }
}

// ---------------- Output projection GEMM: 128(M) x 64(N), BK=64, fp32 out ----------------
__global__ __launch_bounds__(256, 2)
void gemm_o(const u16* __restrict__ A, const u16* __restrict__ W,
            const float* __restrict__ bias, float* __restrict__ O) {
  __shared__ __align__(16) u16 As[128 * 64];
  __shared__ __align__(16) u16 Bs[64 * 64];

  const int L = blockIdx.x + (blockIdx.y << 4);  // 0..511
  const int xcd = L & 7, sl = L >> 3;            // sl 0..63
  const int y = xcd * 4 + (sl >> 4);
  const int x = sl & 15;

  const int tid  = threadIdx.x;
  const int wave = tid >> 6, lane = tid & 63;
  const int quad = lane >> 4, lcol = lane & 15;
  const int m0 = y * 128, n0 = x * 64;
  const int wm = (wave >> 1) * 64, wn = (wave & 1) * 32;
  const int x7 = lcol & 7;

  const int srow = tid >> 3;
  const int scol = ((tid & 7) ^ ((tid >> 3) & 7)) * 8;

  f32x4 acc[4][2] = {};

  for (int k0 = 0; k0 < DMODEL; k0 += 64) {
#pragma unroll
    for (int r = 0; r < 4; ++r) {
      int row = r * 32 + srow;
      const u16* gA = A + (size_t)(m0 + row) * DMODEL + k0 + scol;
      u16* lA = As + (size_t)(r * 256 + (tid & 192)) * 8;
      __builtin_amdgcn_global_load_lds((const __attribute__((address_space(1))) void*)gA,
                                       (__attribute__((address_space(3))) void*)lA, 16, 0, 0);
    }
#pragma unroll
    for (int r = 0; r < 2; ++r) {
      int row = r * 32 + srow;
      const u16* gW = W + (size_t)(n0 + row) * DMODEL + k0 + scol;
      u16* lB = Bs + (size_t)(r * 256 + (tid & 192)) * 8;
      __builtin_amdgcn_global_load_lds((const __attribute__((address_space(1))) void*)gW,
                                       (__attribute__((address_space(3))) void*)lB, 16, 0, 0);
    }
    __syncthreads();

#pragma unroll
    for (int c = 0; c < 2; ++c) {
      const int chk = (((c << 2) | quad) ^ x7) << 3;
      bf16x8 af[4], bfr[2];
#pragma unroll
      for (int i = 0; i < 4; ++i) af[i]  = *(const bf16x8*)(As + (wm + i * 16 + lcol) * 64 + chk);
#pragma unroll
      for (int j = 0; j < 2; ++j) bfr[j] = *(const bf16x8*)(Bs + (wn + j * 16 + lcol) * 64 + chk);
#pragma unroll
      for (int i = 0; i < 4; ++i)
#pragma unroll
        for (int j = 0; j < 2; ++j)
          acc[i][j] = __builtin_amdgcn_mfma_f32_16x16x32_bf16(af[i], bfr[j], acc[i][j], 0, 0, 0);
    }
    __syncthreads();
  }

#pragma unroll
  for (int i = 0; i < 4; ++i) {
#pragma unroll
    for (int j = 0; j < 2; ++j) {
      int n = n0 + wn + j * 16 + lcol;
      float bv = bias[n];
#pragma unroll
      for (int r = 0; r < 4; ++r) {
        int m = m0 + wm + i * 16 + quad * 4 + r;
        O[(size_t)m * DMODEL + n] = acc[i][j][r] + bv;
      }
    }
  }
}

// ---------------- Flash attention v7 (proven 52us): dbuf, gload_lds K, in-reg P ----------------
// Q,K,V: [B*H, S, DK] bf16 (Q pre-scaled by log2 e). Output: [S*B, D] bf16.
// 8 waves/512 thr: qg = wave&3 (32 q-rows), kh = wave>>2 (kv half). Q-tile 128,
// grid 512 = 2 blocks/CU -> 16 waves/CU. Double-buffered K/V, ONE barrier/iter.
// NOTE: no unroll pragma on the main loop — R9 measured that unroll-2 spills the
// conditional cross-barrier prefetch regs to scratch (WRITE_SIZE 8KB -> 124MB, 2x slower).
__global__ __launch_bounds__(512, 4)
void attn_kernel(const u16* __restrict__ Q, const u16* __restrict__ K,
                 const u16* __restrict__ V, u16* __restrict__ O) {
  __shared__ __align__(16) u16 Ks[2][128 * 64];
  __shared__ __align__(16) u16 Vts[2][2 * 4608];
  __shared__ float ls2[4][2][16];

  const int tid  = threadIdx.x;
  const int wave = tid >> 6, lane = tid & 63;
  const int quad = lane >> 4, lcol = lane & 15;
  const int qg = wave & 3;    // q group: 32 rows
  const int kh = wave >> 2;   // kv half

  // bijective XCD swizzle: XCD c gets heads {4c..4c+3} x 16 q-tiles
  const int L = blockIdx.x + (blockIdx.y << 4);  // 0..511
  const int xcd = L & 7, slot = L >> 3;          // slot 0..63
  const int bh = xcd * 4 + (slot >> 4);
  const int q0 = (slot & 15) * 128;

  const size_t headOff = (size_t)bh * S_LEN * DKH;
  const u16* Qg = Q + headOff;
  const u16* Kg = K + headOff;
  const u16* Vg = V + headOff;

  // Q fragments in registers
  bf16x8 qf[2][2];
#pragma unroll
  for (int s = 0; s < 2; ++s)
#pragma unroll
    for (int kc = 0; kc < 2; ++kc)
      qf[s][kc] = *(const bf16x8*)(Qg + (size_t)(q0 + qg * 32 + s * 16 + lcol) * DKH +
                                   kc * 32 + quad * 8);

  // K staging via gload_lds: wave-linear dest, XOR-swizzled source column.
  const int krow = tid >> 3;                                   // 0..63 (local row)
  const int kcs  = (((tid & 7) ^ ((tid >> 3) & 7))) * 8;       // src col (u16)
  const int kdst = (tid & 448) * 8;                            // u16: wave*512 (wave-uniform)
  // V staging roles
  const int vhalf = lane >> 5, vkp = lane & 31, vo = wave;

  // ---- prologue: stage tile 0 -> buf 0
  {
    const u16* vp = Vg + (size_t)(vhalf * (S_LEN / 2) + 2 * vkp) * DKH + 8 * vo;
    uint4 vr0 = *(const uint4*)vp;
    uint4 vr1 = *(const uint4*)(vp + DKH);
    __builtin_amdgcn_global_load_lds(
        (const __attribute__((address_space(1))) void*)(Kg + (size_t)krow * DKH + kcs),
        (__attribute__((address_space(3))) void*)(Ks[0] + kdst), 16, 0, 0);
    __builtin_amdgcn_global_load_lds(
        (const __attribute__((address_space(1))) void*)(Kg + (size_t)(S_LEN / 2 + krow) * DKH + kcs),
        (__attribute__((address_space(3))) void*)(Ks[0] + 4096 + kdst), 16, 0, 0);
    u16* vd = Vts[0] + vhalf * 4608;
#pragma unroll
    for (int jj = 0; jj < 4; ++jj) {
      u32 aw = ((const u32*)&vr0)[jj], bw = ((const u32*)&vr1)[jj];
      *(u32*)(vd + (size_t)(8 * vo + 2 * jj) * 72 + 2 * vkp)     = __builtin_amdgcn_perm(bw, aw, 0x05040100u);
      *(u32*)(vd + (size_t)(8 * vo + 2 * jj + 1) * 72 + 2 * vkp) = __builtin_amdgcn_perm(bw, aw, 0x07060302u);
    }
  }

  f32x4 o_acc[2][4] = {};
  float lsum[2] = {0.f, 0.f};

  for (int it = 0; it < 16; ++it) {
    const int cur = it & 1;
    __syncthreads();  // buf[cur] complete (compiler drains vmcnt+lgkm before s_barrier)

    // prefetch tile it+1 into buf[cur^1]: V->regs, K->LDS direct
    uint4 vr0, vr1;
    const bool has = (it < 15);
    if (has) {
      const int nb = (it + 1) * 64;
      const u16* vp = Vg + (size_t)(vhalf * (S_LEN / 2) + nb + 2 * vkp) * DKH + 8 * vo;
      vr0 = *(const uint4*)vp;
      vr1 = *(const uint4*)(vp + DKH);
      __builtin_amdgcn_global_load_lds(
          (const __attribute__((address_space(1))) void*)(Kg + (size_t)(nb + krow) * DKH + kcs),
          (__attribute__((address_space(3))) void*)(Ks[cur ^ 1] + kdst), 16, 0, 0);
      __builtin_amdgcn_global_load_lds(
          (const __attribute__((address_space(1))) void*)(Kg + (size_t)(S_LEN / 2 + nb + krow) * DKH + kcs),
          (__attribute__((address_space(3))) void*)(Ks[cur ^ 1] + 4096 + kdst), 16, 0, 0);
    }

    const u16* kb = Ks[cur] + kh * 4096;   // this half's 64 rows (swizzled)
    const u16* vb = Vts[cur] + kh * 4608;

    // two 32-key groups; per group: QK -> softmax/pack -> PV
#pragma unroll
    for (int g = 0; g < 2; ++g) {
      bf16x8 ak[2][2];
#pragma unroll
      for (int jb = 0; jb < 2; ++jb)
#pragma unroll
        for (int kc = 0; kc < 2; ++kc)
          ak[jb][kc] = *(const bf16x8*)(kb + (g * 32 + jb * 16 + lcol) * 64 +
                                        ((((kc << 2) | quad) ^ (lcol & 7)) << 3));
      f32x4 sc[2][2] = {};
      __builtin_amdgcn_s_setprio(1);
#pragma unroll
      for (int kc = 0; kc < 2; ++kc)
#pragma unroll
        for (int jb = 0; jb < 2; ++jb)
#pragma unroll
          for (int s = 0; s < 2; ++s)
            sc[jb][s] = __builtin_amdgcn_mfma_f32_16x16x32_bf16(ak[jb][kc], qf[s][kc], sc[jb][s], 0, 0, 0);
      __builtin_amdgcn_s_setprio(0);

      // p = 2^s; pack + permlane redistribute into PV A-frags (in-register P)
      bf16x8 pa[2];
#pragma unroll
      for (int s = 0; s < 2; ++s) {
        u32 ww[2][2];
#pragma unroll
        for (int jb = 0; jb < 2; ++jb) {
          float p0 = EXP2(sc[jb][s][0]);
          float p1 = EXP2(sc[jb][s][1]);
          float p2 = EXP2(sc[jb][s][2]);
          float p3 = EXP2(sc[jb][s][3]);
          lsum[s] += (p0 + p1) + (p2 + p3);
          asm("v_cvt_pk_bf16_f32 %0, %1, %2" : "=v"(ww[jb][0]) : "v"(p0), "v"(p1));
          asm("v_cvt_pk_bf16_f32 %0, %1, %2" : "=v"(ww[jb][1]) : "v"(p2), "v"(p3));
        }
        u32 a0 = ww[0][0], b0 = ww[1][0];
        SWAP32(a0, b0); SWAP16(a0, b0);
        u32 a1 = ww[0][1], b1 = ww[1][1];
        SWAP32(a1, b1); SWAP16(a1, b1);
        union { u32 u[4]; bf16x8 v; } f;
        f.u[0] = a0; f.u[1] = a1; f.u[2] = b0; f.u[3] = b1;
        pa[s] = f.v;
      }

      bf16x8 bv[4];
#pragma unroll
      for (int jd = 0; jd < 4; ++jd)
        bv[jd] = *(const bf16x8*)(vb + (jd * 16 + lcol) * 72 + g * 32 + quad * 8);
      __builtin_amdgcn_s_setprio(1);
#pragma unroll
      for (int s = 0; s < 2; ++s)
#pragma unroll
        for (int jd = 0; jd < 4; ++jd)
          o_acc[s][jd] = __builtin_amdgcn_mfma_f32_16x16x32_bf16(pa[s], bv[jd], o_acc[s][jd], 0, 0, 0);
      __builtin_amdgcn_s_setprio(0);
    }

    // late V publish into buf[cur^1] (loads have had the whole compute to land)
    if (has) {
      u16* vd = Vts[cur ^ 1] + vhalf * 4608;
#pragma unroll
      for (int jj = 0; jj < 4; ++jj) {
        u32 aw = ((const u32*)&vr0)[jj], bw = ((const u32*)&vr1)[jj];
        *(u32*)(vd + (size_t)(8 * vo + 2 * jj) * 72 + 2 * vkp)     = __builtin_amdgcn_perm(bw, aw, 0x05040100u);
        *(u32*)(vd + (size_t)(8 * vo + 2 * jj + 1) * 72 + 2 * vkp) = __builtin_amdgcn_perm(bw, aw, 0x07060302u);
      }
    }
  }

  __syncthreads();  // ALL compute done before LDS is reused as combine scratch

  // reduce lsum over quads
#pragma unroll
  for (int s = 0; s < 2; ++s) {
    lsum[s] += __shfl_xor(lsum[s], 16);
    lsum[s] += __shfl_xor(lsum[s], 32);
  }

  // ---- cross-half combine (scratch on dead Vts: 9216 floats, stride 36 = bank-minimal)
  float* scr = (float*)Vts;
  const int cbase = (qg * 64 + lane) * 36;
  if (kh == 1) {
#pragma unroll
    for (int s = 0; s < 2; ++s)
#pragma unroll
      for (int jd = 0; jd < 4; ++jd)
        *(f32x4*)(scr + cbase + (s * 4 + jd) * 4) = o_acc[s][jd];
    if (lane < 16) {
#pragma unroll
      for (int s = 0; s < 2; ++s) ls2[qg][s][lane] = lsum[s];
    }
  }
  __syncthreads();
  if (kh == 0) {
#pragma unroll
    for (int s = 0; s < 2; ++s)
#pragma unroll
      for (int jd = 0; jd < 4; ++jd)
        o_acc[s][jd] += *(const f32x4*)(scr + cbase + (s * 4 + jd) * 4);

    float tot[2];
#pragma unroll
    for (int s = 0; s < 2; ++s) tot[s] = lsum[s] + ls2[qg][s][lcol];

    // epilogue: normalize, write [S*B, D] bf16
    const int b = bh >> 4, hh = bh & 15;
#pragma unroll
    for (int s = 0; s < 2; ++s) {
#pragma unroll
      for (int r = 0; r < 4; ++r) {
        float inv = 1.f / __shfl(tot[s], quad * 4 + r);  // lane quad*4+r has lcol==quad*4+r
        int sq = q0 + qg * 32 + s * 16 + quad * 4 + r;
#pragma unroll
        for (int jd = 0; jd < 4; ++jd) {
          int dk = jd * 16 + lcol;
          O[((size_t)(sq * BATCH + b)) * DMODEL + hh * DKH + dk] = f2bf(o_acc[s][jd][r] * inv);
        }
      }
    }
  }
}

// ---------------- launch ----------------
extern "C" void kernel_launch(void* const* d_in, const int* in_sizes, int n_in,
                              void* d_out, int out_size, void* d_ws, size_t ws_size,
                              hipStream_t stream) {
  const float* q  = (const float*)d_in[0];
  const float* k  = (const float*)d_in[1];
  const float* v  = (const float*)d_in[2];
  const float* Wq = (const float*)d_in[3];
  const float* bq = (const float*)d_in[4];
  const float* Wk = (const float*)d_in[5];
  const float* bk = (const float*)d_in[6];
  const float* Wv = (const float*)d_in[7];
  const float* bv = (const float*)d_in[8];
  const float* Wo = (const float*)d_in[9];
  const float* bo = (const float*)d_in[10];

  const int NX = S_LEN * BATCH * DMODEL;  // 4194304
  const int NW = DMODEL * DMODEL;         // 1048576

  u16* ws  = (u16*)d_ws;
  u16* Xq  = ws;                    // 3 contiguous activation tensors
  u16* Wqb = Xq  + 3 * (size_t)NX;  // 4 contiguous weight tensors
  u16* Qb  = Wqb + 4 * (size_t)NW;  // 3 contiguous [B,H,S,DK] outputs
  u16* Xo  = Qb  + 3 * (size_t)NX;  // attention out [S*B, D]

  u16* Wob = Wqb + 3 * (size_t)NW;
  u16* Kb  = Qb + NX, *Vb = Qb + 2 * (size_t)NX;

  const int n4 = (3 * NX + 4 * NW) / 4;  // 4194304
  cvt_all<<<n4 / 256, 256, 0, stream>>>((const float4*)q, (const float4*)k, (const float4*)v,
                                        (const float4*)Wq, (const float4*)Wk, (const float4*)Wv,
                                        (const float4*)Wo, (ushort4*)ws);

  dim3 gqkv(DMODEL / 128, (S_LEN * BATCH) / 128, 3);  // 768 blocks
  gemm_qkv<<<gqkv, 256, 0, stream>>>(Xq, Wqb, bq, bk, bv, Qb);

  dim3 ga(S_LEN / 128, BATCH * NHEAD);  // (16, 32) = 512 blocks, 512 threads
  attn_kernel<<<ga, 512, 0, stream>>>(Qb, Kb, Vb, Xo);

  dim3 go(DMODEL / 64, (S_LEN * BATCH) / 128);  // 512 blocks
  gemm_o<<<go, 256, 0, stream>>>(Xo, Wob, bo, (float*)d_out);
}